// Round 4
// baseline (70.335 us; speedup 1.0000x reference)
//
#include <hip/hip_runtime.h>

#define THREADS 256
#define RB      16     // rows per block-chunk
#define LCAP    128    // candidate-list capacity
#define KF      80     // compiled K (harness K=80)
#define K2      160    // 2*KF (C|D)
#define NPART   8      // XCD-aligned partition count
#define MAXBLK  512    // 2 blocks/CU x 256 CUs: guaranteed co-resident

__device__ __forceinline__ unsigned fmap(float x) {   // order-preserving float->uint
  unsigned u = __float_as_uint(x);
  return (u >> 31) ? ~u : (u | 0x80000000u);
}

__global__ __launch_bounds__(THREADS, 2)
void mainK(const float* __restrict__ S, const float* __restrict__ J,
           const float* __restrict__ C, const float* __restrict__ D,
           float tau,
           float* __restrict__ slotPart, int* __restrict__ slotCount,
           int* __restrict__ subctr, int* __restrict__ master, int* __restrict__ gen,
           int* __restrict__ leader, int* __restrict__ lslot,
           float* __restrict__ out, int N, int K) {
  __shared__ int   listIdx[LCAP];
  __shared__ float listVal[LCAP];
  __shared__ int   cnts[THREADS];
  __shared__ unsigned long long rowKey[RB];
  __shared__ int   rowSlot[RB];
  __shared__ int   rowLocal[RB];
  __shared__ int   touchSlot[RB];
  __shared__ int   touchCnt[RB];
  __shared__ float invCnt[RB];
  __shared__ int   unresR[RB];
  __shared__ int   sT, sNT, sNU;
  __shared__ unsigned long long bkey;
  __shared__ float slab[RB * K2];          // 10.2 KB

  const int tid = threadIdx.x;
  const int b   = blockIdx.x;
  const size_t NKc = (size_t)N * K;
  const int p = b & (NPART - 1);

  // ================= A: block-invariant candidate list {j : S[j] >= tau} =================
  int T;
  {
    const bool vec4 = ((N & 3) == 0);
    int cl = 0;
    if (vec4) {
      const int n4 = N >> 2;
      const int per4 = (n4 + THREADS - 1) / THREADS;
      const int a0 = tid * per4, a1 = min(n4, a0 + per4);
      for (int a = a0; a < a1; ++a) {
        float4 v = ((const float4*)S)[a];
        cl += (v.x >= tau) + (v.y >= tau) + (v.z >= tau) + (v.w >= tau);
      }
    } else {
      const int per = (N + THREADS - 1) / THREADS;
      const int j0 = tid * per, j1 = min(N, j0 + per);
      for (int j = j0; j < j1; ++j) cl += (S[j] >= tau);
    }
    cnts[tid] = cl;
    __syncthreads();
    if (tid < 64) {                        // wave-0 exclusive prefix over 256 counts
      const int base = tid * 4;
      int a0 = cnts[base], a1 = cnts[base+1], a2 = cnts[base+2], a3 = cnts[base+3];
      int s = a0 + a1 + a2 + a3;
      int inc = s;
      for (int off = 1; off < 64; off <<= 1) { int o = __shfl_up(inc, off, 64); if (tid >= off) inc += o; }
      int exc = inc - s;
      cnts[base] = exc; cnts[base+1] = exc + a0;
      cnts[base+2] = exc + a0 + a1; cnts[base+3] = exc + a0 + a1 + a2;
      if (tid == 63) sT = inc;
    }
    __syncthreads();
    T = sT;
    const bool fill = (T <= LCAP);
    if (fill) {
      int pos = cnts[tid];
      if (vec4) {
        const int n4 = N >> 2;
        const int per4 = (n4 + THREADS - 1) / THREADS;
        const int a0 = tid * per4, a1 = min(n4, a0 + per4);
        for (int a = a0; a < a1; ++a) {
          float4 v = ((const float4*)S)[a];
          if (v.x >= tau) { listIdx[pos] = a*4+0; listVal[pos] = v.x; ++pos; }
          if (v.y >= tau) { listIdx[pos] = a*4+1; listVal[pos] = v.y; ++pos; }
          if (v.z >= tau) { listIdx[pos] = a*4+2; listVal[pos] = v.z; ++pos; }
          if (v.w >= tau) { listIdx[pos] = a*4+3; listVal[pos] = v.w; ++pos; }
        }
      } else {
        const int per = (N + THREADS - 1) / THREADS;
        const int j0 = tid * per, j1 = min(N, j0 + per);
        for (int j = j0; j < j1; ++j) {
          float v = S[j];
          if (v >= tau) { listIdx[pos] = j; listVal[pos] = v; ++pos; }
        }
      }
    }
  }
  const int ovf = (T > LCAP) | (K != KF);  // unconditional-correctness escape hatch
  __syncthreads();

  // ================= pre-barrier: per-chunk assign + scatter + flush =================
  for (long long cb = b; cb * RB < (long long)N; cb += gridDim.x) {
    const int i0 = (int)(cb * RB);
    if (tid == 0) sNU = 0;
    if (tid < RB) { rowKey[tid] = 0ull; rowSlot[tid] = -1; rowLocal[tid] = -1; }
    __syncthreads();

    // ---- B: leader assign, 16 threads/row over list slots ----
    {
      const int r = tid & (RB - 1);
      const int g = tid >> 4;
      const int i = i0 + r;
      if (!ovf && i < N) {
        unsigned long long lk = 0ull;
        for (int t = g; t < T; t += 16) {
          float v = J[(size_t)listIdx[t] * N + i];   // symmetric J: coalesced column read
          if (v > 0.5f) {
            unsigned long long key = ((unsigned long long)fmap(listVal[t]) << 32)
                                   | (unsigned)(0xFFFFFFFFu - (unsigned)t);
            if (key > lk) lk = key;                  // index-ascending slots: min slot == min index
          }
        }
        if (lk) atomicMax(&rowKey[r], lk);
      }
    }
    __syncthreads();
    if (tid < RB) {
      const int i = i0 + tid;
      if (i < N) {
        unsigned long long k = ovf ? 0ull : rowKey[tid];
        if (k != 0ull) {
          int slot = (int)(0xFFFFFFFFu - (unsigned)(k & 0xFFFFFFFFull));
          rowSlot[tid] = slot;
          __hip_atomic_store(&leader[i], listIdx[slot], __ATOMIC_RELAXED, __HIP_MEMORY_SCOPE_AGENT);
          __hip_atomic_store(&lslot[i], slot, __ATOMIC_RELAXED, __HIP_MEMORY_SCOPE_AGENT);
        } else {
          __hip_atomic_store(&lslot[i], -1, __ATOMIC_RELAXED, __HIP_MEMORY_SCOPE_AGENT);
          int u = atomicAdd(&sNU, 1);
          unresR[u] = tid;
        }
      }
    }
    __syncthreads();

    // ---- B': exact full-row argmax for unresolved rows (expected: none) ----
    const int nu = sNU;
    for (int u = 0; u < nu; ++u) {
      const int rr = unresR[u]; const int ii = i0 + rr;
      if (tid == 0) bkey = 0ull;
      __syncthreads();
      unsigned long long bk = 0ull;
      for (int j = tid; j < N; j += THREADS) {
        float v = J[(size_t)ii * N + j];
        if (v > 0.5f || j == ii) {
          unsigned long long key = ((unsigned long long)fmap(S[j]) << 32)
                                 | (unsigned)(0xFFFFFFFFu - (unsigned)j);
          if (key > bk) bk = key;
        }
      }
      if (bk) atomicMax(&bkey, bk);
      __syncthreads();
      if (tid == 0) {
        int js = (int)(0xFFFFFFFFu - (unsigned)(bkey & 0xFFFFFFFFull));
        __hip_atomic_store(&leader[ii], js, __ATOMIC_RELAXED, __HIP_MEMORY_SCOPE_AGENT);
      }
      __syncthreads();
    }

    // ---- touch map: compact distinct slots of this chunk's rows (<=16) ----
    if (tid == 0) {
      int nt = 0;
      for (int rr = 0; rr < RB; ++rr) {
        int s = rowSlot[rr];
        if (s < 0) continue;
        int loc = -1;
        for (int t = 0; t < nt; ++t) if (touchSlot[t] == s) { loc = t; break; }
        if (loc < 0) { loc = nt++; touchSlot[loc] = s; touchCnt[loc] = 0; }
        touchCnt[loc]++; rowLocal[rr] = loc;
      }
      sNT = nt;
    }
    __syncthreads();
    const int nT = sNT;

    // ---- C: accumulate own rows into compact LDS slab (float4 loads) ----
    for (int idx = tid; idx < nT * K2; idx += THREADS) slab[idx] = 0.f;
    __syncthreads();
    for (int q = tid; q < RB * 40; q += THREADS) {    // 40 float4 per row (C:20|D:20)
      const int rr = q / 40, f = q - rr * 40;
      const int i = i0 + rr;
      if (i >= N) continue;
      const int loc = rowLocal[rr];
      if (loc < 0) continue;
      const float4 v = (f < 20) ? *(const float4*)(C + (size_t)i * KF + f * 4)
                                : *(const float4*)(D + (size_t)i * KF + (f - 20) * 4);
      float* sb = &slab[loc * K2 + (f < 20 ? f * 4 : KF + (f - 20) * 4)];
      atomicAdd(sb + 0, v.x); atomicAdd(sb + 1, v.y);
      atomicAdd(sb + 2, v.z); atomicAdd(sb + 3, v.w);
    }
    __syncthreads();

    // ---- D: flush counts + slab into XCD-aligned partition (b&7 ~ XCD id) ----
    if (tid < nT) atomicAdd(&slotCount[touchSlot[tid]], touchCnt[tid]);
    for (int idx = tid; idx < nT * K2; idx += THREADS) {
      const int loc = idx / K2, k = idx - loc * K2;
      atomicAdd(slotPart + ((size_t)p * LCAP + touchSlot[loc]) * K2 + k, slab[idx]);
    }
    __syncthreads();
  }

  // ================= grid barrier (acq_rel chain -> plain loads legal after) =================
  if (tid == 0) {
    const int nblk = gridDim.x;
    const int expect = (nblk + NPART - 1 - p) / NPART;  // blocks with b%NPART==p
    int o = __hip_atomic_fetch_add(&subctr[p * 16], 1, __ATOMIC_ACQ_REL, __HIP_MEMORY_SCOPE_AGENT);
    if (o == expect - 1) {
      const int nparts = nblk < NPART ? nblk : NPART;
      int o2 = __hip_atomic_fetch_add(master, 1, __ATOMIC_ACQ_REL, __HIP_MEMORY_SCOPE_AGENT);
      if (o2 == nparts - 1)
        __hip_atomic_store(gen, 1, __ATOMIC_RELEASE, __HIP_MEMORY_SCOPE_AGENT);
    }
    while (__hip_atomic_load(gen, __ATOMIC_ACQUIRE, __HIP_MEMORY_SCOPE_AGENT) == 0)
      __builtin_amdgcn_s_sleep(2);
  }
  __syncthreads();

  // ================= post-barrier: per-chunk means + output (plain float4 loads) =================
  for (long long cb = b; cb * RB < (long long)N; cb += gridDim.x) {
    const int i0 = (int)(cb * RB);
    if (tid < RB) {
      const int i = i0 + tid;
      rowSlot[tid]  = (i < N) ? __hip_atomic_load(&lslot[i], __ATOMIC_RELAXED, __HIP_MEMORY_SCOPE_AGENT) : -2;
      rowLocal[tid] = -1;
    }
    __syncthreads();
    if (tid == 0) {
      int nt = 0;
      for (int rr = 0; rr < RB; ++rr) {
        int s = rowSlot[rr];
        if (s < 0) continue;
        int loc = -1;
        for (int t = 0; t < nt; ++t) if (touchSlot[t] == s) { loc = t; break; }
        if (loc < 0) { loc = nt++; touchSlot[loc] = s; }
        rowLocal[rr] = loc;
      }
      sNT = nt;
    }
    __syncthreads();
    const int nT = sNT;

    // reduce 8 partitions into slab — PLAIN float4 loads (L2-cached, post-acquire)
    for (int idx = tid; idx < nT * 40; idx += THREADS) {
      const int loc = idx / 40, f4 = idx - loc * 40;
      const float* base = slotPart + (size_t)touchSlot[loc] * K2 + f4 * 4;
      float4 acc = make_float4(0.f, 0.f, 0.f, 0.f);
      #pragma unroll
      for (int pp = 0; pp < NPART; ++pp) {
        float4 v = *(const float4*)(base + (size_t)pp * LCAP * K2);
        acc.x += v.x; acc.y += v.y; acc.z += v.z; acc.w += v.w;
      }
      *(float4*)(&slab[loc * K2 + f4 * 4]) = acc;
    }
    if (tid < nT) {
      int cc = slotCount[touchSlot[tid]];
      invCnt[tid] = 1.0f / (float)(cc > 0 ? cc : 1);
    }
    __syncthreads();

    for (int q = tid; q < RB * 40; q += THREADS) {
      const int rr = q / 40, f = q - rr * 40;
      const int i = i0 + rr;
      if (i >= N) continue;
      const int loc = rowLocal[rr];
      if (loc < 0) continue;
      const float inv = invCnt[loc];
      const float* sb = &slab[loc * K2 + (f < 20 ? f * 4 : KF + (f - 20) * 4)];
      float4 v = make_float4(sb[0] * inv, sb[1] * inv, sb[2] * inv, sb[3] * inv);
      const size_t off = (f < 20) ? ((size_t)i * KF + f * 4)
                                  : (NKc + (size_t)i * KF + (f - 20) * 4);
      *(float4*)(out + off) = v;                       // contiguous rows: coalesced
    }

    // ---- unresolved rows: exact leader-scan mean (expected: none; any K) ----
    for (int rr = 0; rr < RB; ++rr) {
      if (rowSlot[rr] != -1) continue;
      const int ii = i0 + rr;
      const int m = leader[ii];
      for (int k = tid; k < K; k += THREADS) {
        float sc = 0.f, sd = 0.f; int cc = 0;
        for (int y = 0; y < N; ++y) {
          if (leader[y] == m) { sc += C[(size_t)y * K + k]; sd += D[(size_t)y * K + k]; ++cc; }
        }
        const float inv = 1.0f / (float)(cc > 0 ? cc : 1);
        out[(size_t)ii * K + k] = sc * inv;
        out[NKc + (size_t)ii * K + k] = sd * inv;
      }
    }
    __syncthreads();   // slab/touch arrays reused next chunk
  }
}

extern "C" void kernel_launch(void* const* d_in, const int* in_sizes, int n_in,
                              void* d_out, int out_size, void* d_ws, size_t ws_size,
                              hipStream_t stream) {
  (void)n_in; (void)out_size; (void)ws_size;
  const float* S = (const float*)d_in[0];
  const float* J = (const float*)d_in[1];
  const float* C = (const float*)d_in[2];
  const float* D = (const float*)d_in[3];
  float* out = (float*)d_out;
  const int N = in_sizes[0];
  const int K = in_sizes[2] / N;

  // ws layout (zeroed prefix): slotPart[NPART][LCAP][K2] | slotCount[LCAP] | subctr[128] | master | gen || leader[N] | lslot[N]
  float* slotPart  = (float*)d_ws;
  int*   slotCount = (int*)(slotPart + (size_t)NPART * LCAP * K2);
  int*   subctr    = slotCount + LCAP;
  int*   master    = subctr + 128;
  int*   gen       = master + 1;
  int*   leader    = gen + 1;
  int*   lslot     = leader + N;

  const size_t zbytes = ((size_t)NPART * LCAP * K2 + LCAP + 128 + 2) * sizeof(float);
  hipMemsetAsync(d_ws, 0, zbytes, stream);

  const float tau = 1.0f - 48.0f / (float)N;   // targets E[T]=48; any tau is correct
  int nblk = (N + RB - 1) / RB;
  if (nblk > MAXBLK) nblk = MAXBLK;            // co-residency cap: barrier-safe for any N
  mainK<<<nblk, THREADS, 0, stream>>>(S, J, C, D, tau, slotPart, slotCount,
                                      subctr, master, gen, leader, lslot, out, N, K);
}

// Round 5
// 32.498 us; speedup vs baseline: 2.1643x; 2.1643x over previous
//
#include <hip/hip_runtime.h>

#define THREADS 256
#define RB      16     // rows per block
#define LCAP    128    // candidate-list capacity
#define KF      80     // compiled K (harness K=80)
#define K2      160    // 2*KF (C|D)
#define NPART   8      // partitioned partial sums (b&7 ~ XCD id)

__device__ __forceinline__ unsigned fmap(float x) {   // order-preserving float->uint
  unsigned u = __float_as_uint(x);
  return (u >> 31) ? ~u : (u | 0x80000000u);
}

// ================= mainK: list build + assign + scatter + flush =================
__global__ __launch_bounds__(THREADS)
void mainK(const float* __restrict__ S, const float* __restrict__ J,
           const float* __restrict__ C, const float* __restrict__ D,
           float tau,
           float* __restrict__ slotPart, int* __restrict__ slotCount,
           int* __restrict__ leader, int* __restrict__ lslot,
           int N, int K) {
  __shared__ int   listIdx[LCAP];
  __shared__ float listVal[LCAP];
  __shared__ int   cnts[THREADS];
  __shared__ unsigned long long rowKey[RB];
  __shared__ int   rowSlot[RB];
  __shared__ int   rowLocal[RB];
  __shared__ int   touchSlot[RB];
  __shared__ int   touchCnt[RB];
  __shared__ int   unresR[RB];
  __shared__ int   sT, sNT, sNU;
  __shared__ unsigned long long bkey;
  __shared__ float slab[RB * K2];          // 10.2 KB

  const int tid = threadIdx.x;
  const int b   = blockIdx.x;
  const int i0  = b * RB;

  // ---- A: block-invariant candidate list {j : S[j] >= tau}, index-ascending ----
  int T;
  {
    const bool vec4 = ((N & 3) == 0);
    int cl = 0;
    if (vec4) {
      const int n4 = N >> 2;
      const int per4 = (n4 + THREADS - 1) / THREADS;
      const int a0 = tid * per4, a1 = min(n4, a0 + per4);
      for (int a = a0; a < a1; ++a) {
        float4 v = ((const float4*)S)[a];
        cl += (v.x >= tau) + (v.y >= tau) + (v.z >= tau) + (v.w >= tau);
      }
    } else {
      const int per = (N + THREADS - 1) / THREADS;
      const int j0 = tid * per, j1 = min(N, j0 + per);
      for (int j = j0; j < j1; ++j) cl += (S[j] >= tau);
    }
    cnts[tid] = cl;
    if (tid == 0) { sNU = 0; sNT = 0; }
    __syncthreads();
    if (tid < 64) {                        // wave-0 exclusive prefix over 256 counts
      const int base = tid * 4;
      int a0 = cnts[base], a1 = cnts[base+1], a2 = cnts[base+2], a3 = cnts[base+3];
      int s = a0 + a1 + a2 + a3;
      int inc = s;
      for (int off = 1; off < 64; off <<= 1) { int o = __shfl_up(inc, off, 64); if (tid >= off) inc += o; }
      int exc = inc - s;
      cnts[base] = exc; cnts[base+1] = exc + a0;
      cnts[base+2] = exc + a0 + a1; cnts[base+3] = exc + a0 + a1 + a2;
      if (tid == 63) sT = inc;
    }
    __syncthreads();
    T = sT;
    if (T <= LCAP) {
      int pos = cnts[tid];
      if (vec4) {
        const int n4 = N >> 2;
        const int per4 = (n4 + THREADS - 1) / THREADS;
        const int a0 = tid * per4, a1 = min(n4, a0 + per4);
        for (int a = a0; a < a1; ++a) {
          float4 v = ((const float4*)S)[a];
          if (v.x >= tau) { listIdx[pos] = a*4+0; listVal[pos] = v.x; ++pos; }
          if (v.y >= tau) { listIdx[pos] = a*4+1; listVal[pos] = v.y; ++pos; }
          if (v.z >= tau) { listIdx[pos] = a*4+2; listVal[pos] = v.z; ++pos; }
          if (v.w >= tau) { listIdx[pos] = a*4+3; listVal[pos] = v.w; ++pos; }
        }
      } else {
        const int per = (N + THREADS - 1) / THREADS;
        const int j0 = tid * per, j1 = min(N, j0 + per);
        for (int j = j0; j < j1; ++j) {
          float v = S[j];
          if (v >= tau) { listIdx[pos] = j; listVal[pos] = v; ++pos; }
        }
      }
    }
  }
  const int ovf = (T > LCAP) | (K != KF);  // unconditional-correctness escape hatch
  if (tid < RB) { rowKey[tid] = 0ull; rowSlot[tid] = -1; rowLocal[tid] = -1; }
  __syncthreads();

  // ---- B: leader assign, 16 threads/row over list slots; exact when a top-set nbr exists ----
  {
    const int r = tid & (RB - 1);
    const int g = tid >> 4;
    const int i = i0 + r;
    if (!ovf && i < N) {
      unsigned long long lk = 0ull;
      for (int t = g; t < T; t += 16) {
        const int cand = listIdx[t];
        float v = J[(size_t)cand * N + i];   // symmetric J: coalesced column read
        if (v > 0.5f || cand == i) {         // self always adjacent (eye)
          unsigned long long key = ((unsigned long long)fmap(listVal[t]) << 32)
                                 | (unsigned)(0xFFFFFFFFu - (unsigned)t);
          if (key > lk) lk = key;            // index-ascending slots: min slot == min index
        }
      }
      if (lk) atomicMax(&rowKey[r], lk);
    }
  }
  __syncthreads();
  if (tid < RB) {
    const int i = i0 + tid;
    if (i < N) {
      unsigned long long k = ovf ? 0ull : rowKey[tid];
      if (k != 0ull) {
        int slot = (int)(0xFFFFFFFFu - (unsigned)(k & 0xFFFFFFFFull));
        rowSlot[tid] = slot;
        leader[i] = listIdx[slot];           // plain store: kernel boundary syncs
        lslot[i]  = slot;
      } else {
        lslot[i] = -1;
        int u = atomicAdd(&sNU, 1);
        unresR[u] = tid;
      }
    }
  }
  __syncthreads();

  // ---- B': exact full-row argmax for unresolved rows (expected: none) ----
  const int nu = sNU;
  for (int u = 0; u < nu; ++u) {
    const int rr = unresR[u]; const int ii = i0 + rr;
    if (tid == 0) bkey = 0ull;
    __syncthreads();
    unsigned long long bk = 0ull;
    for (int j = tid; j < N; j += THREADS) {
      float v = J[(size_t)ii * N + j];
      if (v > 0.5f || j == ii) {
        unsigned long long key = ((unsigned long long)fmap(S[j]) << 32)
                               | (unsigned)(0xFFFFFFFFu - (unsigned)j);
        if (key > bk) bk = key;
      }
    }
    if (bk) atomicMax(&bkey, bk);
    __syncthreads();
    if (tid == 0) {
      leader[ii] = (int)(0xFFFFFFFFu - (unsigned)(bkey & 0xFFFFFFFFull));
    }
    __syncthreads();
  }

  // ---- touch map: wave-parallel dedupe of this block's slots (<=16 distinct) ----
  if (tid < RB) {
    int s = rowSlot[tid];
    int first = tid;
    if (s >= 0) { first = 0; while (rowSlot[first] != s) ++first; }
    unsigned long long m = __ballot(s >= 0 && first == tid);
    if (s >= 0) {
      int loc = (int)__popcll(m & ((1ull << first) - 1ull));
      rowLocal[tid] = loc;
      if (first == tid) {
        int cnt = 0;
        for (int rr = 0; rr < RB; ++rr) cnt += (rowSlot[rr] == s);
        touchSlot[loc] = s; touchCnt[loc] = cnt;
      }
    }
    if (tid == 0) sNT = (int)__popcll(m);
  }
  __syncthreads();
  const int nT = sNT;

  // ---- C: accumulate own rows into compact LDS slab (float4 loads) ----
  for (int idx = tid; idx < nT * K2; idx += THREADS) slab[idx] = 0.f;
  __syncthreads();
  for (int q = tid; q < RB * 40; q += THREADS) {      // 40 float4 per row (C:20|D:20)
    const int rr = q / 40, f = q - rr * 40;
    const int i = i0 + rr;
    if (i >= N) continue;
    const int loc = rowLocal[rr];
    if (loc < 0) continue;
    const float4 v = (f < 20) ? *(const float4*)(C + (size_t)i * KF + f * 4)
                              : *(const float4*)(D + (size_t)i * KF + (f - 20) * 4);
    float* sb = &slab[loc * K2 + (f < 20 ? f * 4 : KF + (f - 20) * 4)];
    atomicAdd(sb + 0, v.x); atomicAdd(sb + 1, v.y);
    atomicAdd(sb + 2, v.z); atomicAdd(sb + 3, v.w);
  }
  __syncthreads();

  // ---- D: flush counts + touched slots into partition b&7 ----
  if (tid < nT) atomicAdd(&slotCount[touchSlot[tid]], touchCnt[tid]);
  {
    const int p = b & (NPART - 1);
    for (int idx = tid; idx < nT * K2; idx += THREADS) {
      const int loc = idx / K2, k = idx - loc * K2;
      atomicAdd(slotPart + ((size_t)p * LCAP + touchSlot[loc]) * K2 + k, slab[idx]);
    }
  }
}

// ================= finalizeK: out[i,k] = sum[leader]/count (float4, full occupancy) =================
__global__ __launch_bounds__(THREADS)
void finalizeK(const float* __restrict__ slotPart, const int* __restrict__ slotCount,
               const int* __restrict__ leader, const int* __restrict__ lslot,
               const float* __restrict__ C, const float* __restrict__ D,
               float* __restrict__ out, int N, int K) {
  const int NK4 = N * K / 4;
  int idx = blockIdx.x * THREADS + threadIdx.x;
  if (idx >= 2 * NK4) return;
  const bool isD = (idx >= NK4);
  const int rem = isD ? idx - NK4 : idx;
  const int kq = K / 4;
  const int i  = rem / kq;
  const int k0 = (rem - i * kq) * 4;
  const int slot = lslot[i];
  float4 acc;
  if (slot >= 0) {
    acc = make_float4(0.f, 0.f, 0.f, 0.f);
    const float* base = slotPart + (size_t)slot * K2 + (isD ? KF : 0) + k0;
    #pragma unroll
    for (int p = 0; p < NPART; ++p) {
      float4 v = *(const float4*)(base + (size_t)p * LCAP * K2);
      acc.x += v.x; acc.y += v.y; acc.z += v.z; acc.w += v.w;
    }
    const int c = slotCount[slot];
    const float inv = 1.0f / (float)(c > 0 ? c : 1);
    acc.x *= inv; acc.y *= inv; acc.z *= inv; acc.w *= inv;
  } else {
    // exact leader-scan mean (expected never; correctness escape hatch)
    const int m = leader[i];
    const float* src = isD ? D : C;
    float s0 = 0.f, s1 = 0.f, s2 = 0.f, s3 = 0.f; int cc = 0;
    for (int y = 0; y < N; ++y) {
      if (leader[y] == m) {
        const float* r = src + (size_t)y * K + k0;
        s0 += r[0]; s1 += r[1]; s2 += r[2]; s3 += r[3]; ++cc;
      }
    }
    const float inv = 1.0f / (float)(cc > 0 ? cc : 1);
    acc = make_float4(s0 * inv, s1 * inv, s2 * inv, s3 * inv);
  }
  ((float4*)out)[idx] = acc;
}

extern "C" void kernel_launch(void* const* d_in, const int* in_sizes, int n_in,
                              void* d_out, int out_size, void* d_ws, size_t ws_size,
                              hipStream_t stream) {
  (void)n_in; (void)out_size; (void)ws_size;
  const float* S = (const float*)d_in[0];
  const float* J = (const float*)d_in[1];
  const float* C = (const float*)d_in[2];
  const float* D = (const float*)d_in[3];
  float* out = (float*)d_out;
  const int N = in_sizes[0];
  const int K = in_sizes[2] / N;
  const int NK = N * K;

  // ws layout (zeroed prefix): slotPart[NPART][LCAP][K2] | slotCount[LCAP] || leader[N] | lslot[N]
  float* slotPart  = (float*)d_ws;
  int*   slotCount = (int*)(slotPart + (size_t)NPART * LCAP * K2);
  int*   leader    = slotCount + LCAP;
  int*   lslot     = leader + N;

  const size_t zbytes = ((size_t)NPART * LCAP * K2 + LCAP) * sizeof(float);   // 656 KB
  hipMemsetAsync(d_ws, 0, zbytes, stream);

  const float tau = 1.0f - 48.0f / (float)N;   // targets E[T]=48; any tau is correct
  const int nblk = (N + RB - 1) / RB;          // 512 blocks for N=8192
  mainK<<<nblk, THREADS, 0, stream>>>(S, J, C, D, tau, slotPart, slotCount,
                                      leader, lslot, N, K);
  finalizeK<<<(2 * (NK / 4) + THREADS - 1) / THREADS, THREADS, 0, stream>>>(
      slotPart, slotCount, leader, lslot, C, D, out, N, K);
}